// Round 10
// baseline (278.346 us; speedup 1.0000x reference)
//
#include <hip/hip_runtime.h>

#define ROWS 4096
#define NCOL 8192
#define ROW_F4 (NCOL / 4)            // 2048 float4 per row
#define HALF_F4 1024                 // float4 per half-row (16 KiB)
#define NHALF (ROWS * 2)             // 8192 half-rows
#define K1_THREADS 256
#define K1_BLOCKS (NHALF / 4)        // 2048 blocks x 4 waves, 1 half-row per wave
#define CAP 256

// ---------------- K1: pure copy-shaped stream, register-only reduction ----------------
// Wave w owns half-row h: reads 16 KiB, writes 16 KiB of zeros to out, and each lane
// keeps a private max over its 16 strided float4. ZERO cross-lane operations.
__global__ __launch_bounds__(K1_THREADS, 8)
void sweep_kernel(const float* __restrict__ x, float* __restrict__ out,
                  float* __restrict__ cmax) {
    const int tid  = threadIdx.x;
    const int wave = tid >> 6;
    const int lane = tid & 63;
    const int h    = blockIdx.x * 4 + wave;               // half-row id 0..8191
    const float4* __restrict__ xr = (const float4*)x   + (size_t)h * HALF_F4 + lane;
    float4* __restrict__ orr      = (float4*)out       + (size_t)h * HALF_F4 + lane;
    const float4 z = make_float4(0.0f, 0.0f, 0.0f, 0.0f);

    float m = -INFINITY;
#pragma unroll
    for (int j = 0; j < 16; ++j) {
        float4 q = xr[64 * j];
        orr[64 * j] = z;                                  // fused zero-fill of out
        m = fmaxf(m, fmaxf(fmaxf(q.x, q.y), fmaxf(q.z, q.w)));
    }
    // one coalesced 4-B store per thread: cmax[h*64+lane] == cmax[global_tid]
    cmax[(size_t)h * 64 + lane] = m;
}

// ---------------- K2: per-row solve + sparse fixup (all ds-latency lives here) --------
// One wave per row. Chunk = (half, lane) = 64 elements at stride 64 f4 within a half.
__global__ __launch_bounds__(64)
void solve_kernel(const float* __restrict__ x, float* __restrict__ out,
                  const float* __restrict__ cmax) {
    const int row = blockIdx.x;
    const int L   = threadIdx.x;                          // 0..63
    __shared__ float cand[CAP];
    __shared__ int   scnt;
    if (L == 0) scnt = 0;
    __syncthreads();                                      // 1-wave block: ~free

    // rowmax from the 128 per-thread chunk maxes
    const float c0 = cmax[(size_t)row * 128 + L];
    const float c1 = cmax[(size_t)row * 128 + 64 + L];
    float rm = fmaxf(c0, c1);
#pragma unroll
    for (int off = 32; off > 0; off >>= 1) rm = fmaxf(rm, __shfl_xor(rm, off, 64));
    const float thr = rm - 1.0f;                          // tau* >= rowmax - 1

    const float4* __restrict__ xrow = (const float4*)x + (size_t)row * ROW_F4;

    unsigned long long m0 = __ballot(c0 > thr);           // hot chunks, half 0
    unsigned long long m1 = __ballot(c1 > thr);           // hot chunks, half 1
    const int nhot = __builtin_popcountll(m0) + __builtin_popcountll(m1);

    float t = thr;
    bool fallback = (nhot > 64);                          // astronomically rare

    float a0 = -INFINITY, a1 = -INFINITY, a2 = -INFINITY, a3 = -INFINITY;
    float e  = -INFINITY;                                 // evicted max (processed chunks)
    int myHalf = -1, myChunk = -1;

    if (!fallback) {
        // assign hot chunk #L to lane L (masks are wave-uniform)
        int idx = 0;
        unsigned long long mm = m0;
        while (mm) { int c = __builtin_ctzll(mm); mm &= mm - 1;
                     if (idx == L) { myChunk = c; myHalf = 0; } ++idx; }
        mm = m1;
        while (mm) { int c = __builtin_ctzll(mm); mm &= mm - 1;
                     if (idx == L) { myChunk = c; myHalf = 1; } ++idx; }

        if (myChunk >= 0) {
            const float4* xc = xrow + (size_t)myHalf * HALF_F4 + myChunk;
#define INS(qv) do {                                    \
        float n = (qv), mx;                             \
        mx = fmaxf(a0, n); n = fminf(a0, n); a0 = mx;   \
        mx = fmaxf(a1, n); n = fminf(a1, n); a1 = mx;   \
        mx = fmaxf(a2, n); n = fminf(a2, n); a2 = mx;   \
        mx = fmaxf(a3, n); n = fminf(a3, n); a3 = mx;   \
        e = fmaxf(e, n);                                \
    } while (0)
#pragma unroll
            for (int j = 0; j < 16; ++j) {
                float4 q = xc[64 * j];
                INS(q.x); INS(q.y); INS(q.z); INS(q.w);
            }
#undef INS
        }

        // push candidates > thr (structurally <= 64*4 = 256, never overflows)
        if (a0 > thr) { int p = atomicAdd(&scnt, 1); cand[p] = a0; }
        if (a1 > thr) { int p = atomicAdd(&scnt, 1); cand[p] = a1; }
        if (a2 > thr) { int p = atomicAdd(&scnt, 1); cand[p] = a2; }
        if (a3 > thr) { int p = atomicAdd(&scnt, 1); cand[p] = a3; }
        __syncthreads();
        const int k0 = scnt;                              // >= 1 (rowmax's chunk is hot)

        // shuffle Michelot on the candidate list (identical across lanes)
        const float p0 = (L       < k0) ? cand[L      ] : -INFINITY;
        const float p1 = (L + 64  < k0) ? cand[L + 64 ] : -INFINITY;
        const float p2 = (L + 128 < k0) ? cand[L + 128] : -INFINITY;
        const float p3 = (L + 192 < k0) ? cand[L + 192] : -INFINITY;
        int prev = -1;
        for (int it = 0; it < 64; ++it) {
            float s = 0.0f; int k = 0;
            if (p0 > t) { s += p0; ++k; }
            if (p1 > t) { s += p1; ++k; }
            if (p2 > t) { s += p2; ++k; }
            if (p3 > t) { s += p3; ++k; }
#pragma unroll
            for (int off = 32; off > 0; off >>= 1) {
                s += __shfl_xor(s, off, 64);
                k += __shfl_xor(k, off, 64);
            }
            if (k == prev) break;                         // fixed point reached
            prev = k;
            t = (s - 1.0f) / (float)k;
        }
        // KKT validity: every value absent from the list is <= max(thr, e).
        // thr <= t always; so if e <= t, t satisfies the TRUE simplex equation.
        float be = e;
#pragma unroll
        for (int off = 32; off > 0; off >>= 1) be = fmaxf(be, __shfl_xor(be, off, 64));
        fallback = (be > t);
    }

    if (fallback) {
        // exact full-row Michelot from the valid lower bound thr
        t = thr;
        int prev = -1;
        for (int it = 0; it < 200; ++it) {
            float s = 0.0f; int k = 0;
            for (int j = 0; j < 32; ++j) {
                float4 q = xrow[L + 64 * j];
                if (q.x > t) { s += q.x; ++k; }
                if (q.y > t) { s += q.y; ++k; }
                if (q.z > t) { s += q.z; ++k; }
                if (q.w > t) { s += q.w; ++k; }
            }
#pragma unroll
            for (int off = 32; off > 0; off >>= 1) {
                s += __shfl_xor(s, off, 64);
                k += __shfl_xor(k, off, 64);
            }
            if (k == prev) break;
            prev = k;
            t = (s - 1.0f) / (float)k;
        }
        // fixup over the whole row (out already zeroed by K1)
        for (int j = 0; j < 32; ++j) {
            float4 q = xrow[L + 64 * j];
            const size_t b = (size_t)row * NCOL + ((size_t)L + 64 * j) * 4;
            if (q.x > t) out[b    ] = q.x - t;
            if (q.y > t) out[b + 1] = q.y - t;
            if (q.z > t) out[b + 2] = q.z - t;
            if (q.w > t) out[b + 3] = q.w - t;
        }
    } else if (myChunk >= 0) {
        // sparse fixup: support values live only in hot chunks (support > t >= thr)
        const float4* xc = xrow + (size_t)myHalf * HALF_F4 + myChunk;
        const size_t cbase = (size_t)row * NCOL + (size_t)myHalf * (HALF_F4 * 4);
#pragma unroll
        for (int j = 0; j < 16; ++j) {
            float4 q = xc[64 * j];                        // L2-hot re-read
            const size_t b = cbase + ((size_t)myChunk + 64 * j) * 4;
            if (q.x > t) out[b    ] = q.x - t;
            if (q.y > t) out[b + 1] = q.y - t;
            if (q.z > t) out[b + 2] = q.z - t;
            if (q.w > t) out[b + 3] = q.w - t;
        }
    }
}

extern "C" void kernel_launch(void* const* d_in, const int* in_sizes, int n_in,
                              void* d_out, int out_size, void* d_ws, size_t ws_size,
                              hipStream_t stream) {
    const float* x = (const float*)d_in[0];
    float* out = (float*)d_out;
    float* cmax = (float*)d_ws;     // 8192*64 floats = 2 MiB workspace

    sweep_kernel<<<K1_BLOCKS, K1_THREADS, 0, stream>>>(x, out, cmax);
    solve_kernel<<<ROWS, 64, 0, stream>>>(x, out, cmax);
}

// Round 11
// 230.867 us; speedup vs baseline: 1.2057x; 1.2057x over previous
//
#include <hip/hip_runtime.h>

#define ROWS 4096
#define NCOL 8192
#define THREADS 256
#define WAVES (THREADS / 64)        // 4
#define F4PT (NCOL / (THREADS * 4)) // 8 float4 per thread
#define LDSF4 6                     // float4/thread staged in LDS (j=0..5); j=6,7 stay in regs
#define CAP 256                     // candidate list capacity

__global__ __launch_bounds__(THREADS, 6)
void sparsemax_kernel(const float* __restrict__ x, float* __restrict__ out) {
    const int row  = blockIdx.x;
    const int tid  = threadIdx.x;
    const int wave = tid >> 6;
    const int lane = tid & 63;
    const size_t base = (size_t)row * NCOL;
    const float4* __restrict__ xr = (const float4*)(x + base);
    float4* __restrict__ outr     = (float4*)(out + base);

    __shared__ float4 srow[THREADS * LDSF4];  // 24 KiB: thread-private row stash
    __shared__ float swm[WAVES];   // wave max
    __shared__ float swe[WAVES];   // wave evicted-max
    __shared__ float cand[CAP];
    __shared__ int   scnt;
    __shared__ float swv[WAVES];   // fallback partial sum
    __shared__ int   swk[WAVES];   // fallback partial count

    if (tid == 0) scnt = 0;

    // ---- Pass 1: the ONLY global scan. Online top-4 + evicted max; stash row in LDS.
    float c0 = -INFINITY, c1 = -INFINITY, c2 = -INFINITY, c3 = -INFINITY;
    float e  = -INFINITY;   // max of values evicted from the top-4 (thread's 5th largest)
    float4 v6, v7;          // last two float4 kept in registers (LDS budget: 6 blocks/CU)

#define INS(qv) do {                                    \
        float n = (qv), mx;                             \
        mx = fmaxf(c0, n); n = fminf(c0, n); c0 = mx;   \
        mx = fmaxf(c1, n); n = fminf(c1, n); c1 = mx;   \
        mx = fmaxf(c2, n); n = fminf(c2, n); c2 = mx;   \
        mx = fmaxf(c3, n); n = fminf(c3, n); c3 = mx;   \
        e = fmaxf(e, n);                                \
    } while (0)

#pragma unroll
    for (int j = 0; j < LDSF4; ++j) {
        float4 q = xr[tid + THREADS * j];
        srow[tid + THREADS * j] = q;          // each thread reads back ONLY its own slots
        INS(q.x); INS(q.y); INS(q.z); INS(q.w);
    }
    v6 = xr[tid + THREADS * 6];
    INS(v6.x); INS(v6.y); INS(v6.z); INS(v6.w);
    v7 = xr[tid + THREADS * 7];
    INS(v7.x); INS(v7.y); INS(v7.z); INS(v7.w);
#undef INS

    // ---- Block max + block evicted-max ----
    float m = c0, ew = e;
#pragma unroll
    for (int off = 32; off > 0; off >>= 1) {
        m  = fmaxf(m,  __shfl_xor(m,  off, 64));
        ew = fmaxf(ew, __shfl_xor(ew, off, 64));
    }
    if (lane == 0) { swm[wave] = m; swe[wave] = ew; }
    __syncthreads();                                   // (1) also covers scnt init
    float bm = swm[0], be = swe[0];
#pragma unroll
    for (int w = 1; w < WAVES; ++w) { bm = fmaxf(bm, swm[w]); be = fmaxf(be, swe[w]); }
    const float t0 = bm - 1.0f;   // tau* >= max-1

    // ---- Push candidates (> t0) from per-thread top-4 (expected ~21 total) ----
    if (c0 > t0) { int p = atomicAdd(&scnt, 1); if (p < CAP) cand[p] = c0; }
    if (c1 > t0) { int p = atomicAdd(&scnt, 1); if (p < CAP) cand[p] = c1; }
    if (c2 > t0) { int p = atomicAdd(&scnt, 1); if (p < CAP) cand[p] = c2; }
    if (c3 > t0) { int p = atomicAdd(&scnt, 1); if (p < CAP) cand[p] = c3; }
    __syncthreads();                                   // (2) last barrier in fast path

    const int k0 = scnt;
    float t = t0;
    bool need_full = (k0 > CAP);

    if (!need_full) {
        // Wave-redundant Michelot on the tiny list: shuffle-only, no barriers,
        // deterministic identical result in every wave.
        const float q0 = (lane       < k0) ? cand[lane      ] : -INFINITY;
        const float q1 = (lane + 64  < k0) ? cand[lane + 64 ] : -INFINITY;
        const float q2 = (lane + 128 < k0) ? cand[lane + 128] : -INFINITY;
        const float q3 = (lane + 192 < k0) ? cand[lane + 192] : -INFINITY;
        int prev_k = -1;
        for (int it = 0; it < 64; ++it) {
            float s = 0.0f; int k = 0;
            if (q0 > t) { s += q0; ++k; }
            if (q1 > t) { s += q1; ++k; }
            if (q2 > t) { s += q2; ++k; }
            if (q3 > t) { s += q3; ++k; }
#pragma unroll
            for (int off = 32; off > 0; off >>= 1) {
                s += __shfl_xor(s, off, 64);
                k += __shfl_xor(k, off, 64);
            }
            if (k == prev_k) break;        // support stable => t is the fixed point
            prev_k = k;
            t = (s - 1.0f) / (float)k;
        }
        // Validity: if any thread's evicted max exceeds tau, the candidate union
        // may have missed support elements -> exact fallback.
        need_full = (be > t);
    }

    if (need_full) {
        // ---- Exact fallback (cold: needs >=5 support values in one thread) ----
        // Block-wide Michelot; row comes from LDS + the two register float4s.
        int prev_k = -1;
        for (int it = 0; it < 200; ++it) {
            float s = 0.0f; int k = 0;
#pragma unroll
            for (int j = 0; j < LDSF4; ++j) {
                float4 q = srow[tid + THREADS * j];
                if (q.x > t) { s += q.x; ++k; }
                if (q.y > t) { s += q.y; ++k; }
                if (q.z > t) { s += q.z; ++k; }
                if (q.w > t) { s += q.w; ++k; }
            }
            if (v6.x > t) { s += v6.x; ++k; }
            if (v6.y > t) { s += v6.y; ++k; }
            if (v6.z > t) { s += v6.z; ++k; }
            if (v6.w > t) { s += v6.w; ++k; }
            if (v7.x > t) { s += v7.x; ++k; }
            if (v7.y > t) { s += v7.y; ++k; }
            if (v7.z > t) { s += v7.z; ++k; }
            if (v7.w > t) { s += v7.w; ++k; }
#pragma unroll
            for (int off = 32; off > 0; off >>= 1) {
                s += __shfl_xor(s, off, 64);
                k += __shfl_xor(k, off, 64);
            }
            if (lane == 0) { swv[wave] = s; swk[wave] = k; }
            __syncthreads();
            float st = 0.0f; int kt = 0;
#pragma unroll
            for (int w = 0; w < WAVES; ++w) { st += swv[w]; kt += swk[w]; }
            __syncthreads();
            if (kt == prev_k) break;       // uniform decision across block
            prev_k = kt;
            t = (st - 1.0f) / (float)kt;
        }
    }

    // ---- Epilogue: row from LDS/regs (NO global re-read), plain stores ----
#pragma unroll
    for (int j = 0; j < LDSF4; ++j) {
        float4 q = srow[tid + THREADS * j];   // own slots: no barrier needed
        float4 r;
        r.x = fmaxf(q.x - t, 0.0f);
        r.y = fmaxf(q.y - t, 0.0f);
        r.z = fmaxf(q.z - t, 0.0f);
        r.w = fmaxf(q.w - t, 0.0f);
        outr[tid + THREADS * j] = r;
    }
    {
        float4 r;
        r.x = fmaxf(v6.x - t, 0.0f);
        r.y = fmaxf(v6.y - t, 0.0f);
        r.z = fmaxf(v6.z - t, 0.0f);
        r.w = fmaxf(v6.w - t, 0.0f);
        outr[tid + THREADS * 6] = r;
        r.x = fmaxf(v7.x - t, 0.0f);
        r.y = fmaxf(v7.y - t, 0.0f);
        r.z = fmaxf(v7.z - t, 0.0f);
        r.w = fmaxf(v7.w - t, 0.0f);
        outr[tid + THREADS * 7] = r;
    }
}

extern "C" void kernel_launch(void* const* d_in, const int* in_sizes, int n_in,
                              void* d_out, int out_size, void* d_ws, size_t ws_size,
                              hipStream_t stream) {
    const float* x = (const float*)d_in[0];
    float* out = (float*)d_out;
    sparsemax_kernel<<<ROWS, THREADS, 0, stream>>>(x, out);
}